// Round 5
// baseline (796.542 us; speedup 1.0000x reference)
//
#include <hip/hip_runtime.h>
#include <hip/hip_bf16.h>
#include <math.h>

typedef __attribute__((ext_vector_type(8))) short bf16x8;
typedef __attribute__((ext_vector_type(4))) float f32x4;

__device__ __forceinline__ float b2f(unsigned short u) {
    unsigned int v = ((unsigned int)u) << 16;
    return __uint_as_float(v);
}
__device__ __forceinline__ unsigned short f2b(float f) {
    __hip_bfloat16 h = __float2bfloat16(f);
    return *reinterpret_cast<unsigned short*>(&h);
}
// truncation split: hi = top 16 bits, lo = RNE(v - hi). residual ~2^-17 |v|
__device__ __forceinline__ void split_trunc(float v, short& h, short& l) {
    unsigned int ui = __float_as_uint(v);
    h = (short)(ui >> 16);
    float hf = __uint_as_float(ui & 0xffff0000u);
    l = (short)f2b(v - hf);
}

// ============ prep_all: all weight reshapes in ONE kernel ============
// blocks [0,392): fc_w[(c*49+p)*512+n] -> fcw[n][(p*64+c)] bf16 hi/lo
// blocks [392,3464): expert w1/w2 [e][d][h] -> bf16 [e][h][d]
// blocks [3464,3912): conv weights + ew3 transpose (scalar indexed)
__global__ __launch_bounds__(256) void prep_all(
    const float* __restrict__ w1, const float* __restrict__ w2, const float* __restrict__ w3,
    const float* __restrict__ ew3, const float* __restrict__ fw,
    const float* __restrict__ ew1, const float* __restrict__ ew2,
    unsigned short* __restrict__ wb1h, unsigned short* __restrict__ wb1l,
    unsigned short* __restrict__ w2h, unsigned short* __restrict__ w2l,
    unsigned short* __restrict__ w3h, unsigned short* __restrict__ w3l,
    float* __restrict__ w3t,
    unsigned short* __restrict__ fcwh, unsigned short* __restrict__ fcwl,
    unsigned short* __restrict__ ew1t, unsigned short* __restrict__ ew2t) {
    __shared__ float tile[64 * 65];
    int bid = blockIdx.x;
    int t = threadIdx.x;
    if (bid < 392) {
        int k0 = (bid % 49) * 64, n0 = (bid / 49) * 64;
        int tx = t & 63, ty = t >> 6;
#pragma unroll
        for (int j = 0; j < 16; j++) {
            int kk = ty + j * 4;
            int kp = k0 + kk;
            int p = kp >> 6, c = kp & 63;
            tile[kk * 65 + tx] = fw[(c * 49 + p) * 512 + n0 + tx];
        }
        __syncthreads();
#pragma unroll
        for (int j = 0; j < 16; j++) {
            int r = ty + j * 4;
            float v = tile[tx * 65 + r];
            unsigned short hh = f2b(v);
            long d = (long)(n0 + r) * 3136 + k0 + tx;
            fcwh[d] = hh;
            fcwl[d] = f2b(v - b2f(hh));
        }
    } else if (bid < 392 + 3072) {
        int q = bid - 392;
        int z = q >> 8, rem = q & 255;
        int d0 = (rem >> 4) * 32;
        int h0 = (rem & 15) * 32;
        int e = z % 6;
        const float* src = (z < 6) ? (ew1 + e * 262144) : (ew2 + e * 262144);
        unsigned short* dst = (z < 6) ? (ew1t + e * 262144) : (ew2t + e * 262144);
        int tx = t & 31, ty = t >> 5;
#pragma unroll
        for (int j = 0; j < 4; j++)
            tile[(ty + j * 8) * 33 + tx] = src[(d0 + ty + j * 8) * 512 + h0 + tx];
        __syncthreads();
#pragma unroll
        for (int j = 0; j < 4; j++)
            dst[(h0 + ty + j * 8) * 512 + (d0 + tx)] = f2b(tile[tx * 33 + ty + j * 8]);
    } else {
        int tid = (bid - 3464) * 256 + t;
        if (tid < 8192) {
            int k = tid >> 8, r = tid & 255;
            int c = r >> 6, ky = (r >> 3) & 7, kx = r & 7;
            float v = w1[tid];
            unsigned short h = f2b(v);
            int d = ((ky * 2 + (k >> 4)) * 16 + (k & 15)) * 32 + c * 8 + kx;
            wb1h[d] = h;
            wb1l[d] = f2b(v - b2f(h));
        } else if (tid < 8192 + 32768) {
            int i = tid - 8192;
            int n = i >> 9, r = i & 511;
            int c = r >> 4, ky = (r >> 2) & 3, kx = r & 3;
            float v = w2[i];
            unsigned short h = f2b(v);
            int d = ((ky * 4 + kx) * 64 + n) * 32 + c;
            w2h[d] = h;
            w2l[d] = f2b(v - b2f(h));
        } else if (tid < 8192 + 32768 + 36864) {
            int i = tid - 40960;
            int n = i / 576, r = i - n * 576;
            int c = r / 9, s = r - c * 9;
            int ky = s / 3, kx = s - ky * 3;
            float v = w3[i];
            unsigned short h = f2b(v);
            int d = (((ky * 3 + kx) * 2 + (c >> 5)) * 64 + n) * 32 + (c & 31);
            w3h[d] = h;
            w3l[d] = f2b(v - b2f(h));
        } else if (tid < 77824 + 36864) {
            int i = tid - 77824;
            int e = i / 6144, rem = i - e * 6144;
            int a = rem >> 9, k = rem & 511;
            w3t[i] = ew3[e * 6144 + k * 12 + a];
        }
    }
}

// ============ conv1: LDS-staged MFMA, half image per block ============
// block: image n = bid>>1, half h = bid&1; stages 4ch x 44rows x 84cols fp32 (59 KB)
__global__ __launch_bounds__(256, 2) void conv1_k(
    const float* __restrict__ x, const unsigned short* __restrict__ wbh,
    const unsigned short* __restrict__ wbl, const float* __restrict__ b1,
    unsigned short* __restrict__ yhi, unsigned short* __restrict__ ylo) {
    __shared__ float xs[14784];  // [c][44][84]
    int n = blockIdx.x >> 1, h = blockIdx.x & 1;
    int t = threadIdx.x;
    // stage: per c, 3696 floats contiguous from x + (n*4+c)*7056 + h*3360 (16B aligned)
#pragma unroll
    for (int c = 0; c < 4; c++) {
        const float4* src = (const float4*)x + (long)(n * 4 + c) * 1764 + h * 840;
        float4* dst = (float4*)xs + c * 924;
        for (int i = t; i < 924; i += 256) dst[i] = src[i];
    }
    __syncthreads();
    int wave = t >> 6, lane = t & 63, l16 = lane & 15, quad = lane >> 4;
    // tiles: wave w handles tiles w, w+4, w+8, w+12 (tile<=12 valid; tile 12 half-full)
    int pyr[4], oxr[4];
#pragma unroll
    for (int ti = 0; ti < 4; ti++) {
        int tile = wave + ti * 4;
        int p = tile * 16 + l16;
        p = p > 199 ? 199 : p;
        pyr[ti] = p / 20;
        oxr[ti] = p - pyr[ti] * 20;
    }
    f32x4 acc[4][2];
#pragma unroll
    for (int i = 0; i < 4; i++)
#pragma unroll
        for (int j = 0; j < 2; j++)
#pragma unroll
            for (int r = 0; r < 4; r++) acc[i][j][r] = 0.f;
#pragma unroll 2
    for (int ky = 0; ky < 8; ky++) {
        int wo = (ky * 32 + l16) * 32 + quad * 8;
        bf16x8 bh0 = *(const bf16x8*)(wbh + wo);
        bf16x8 bh1 = *(const bf16x8*)(wbh + wo + 512);
        bf16x8 bl0 = *(const bf16x8*)(wbl + wo);
        bf16x8 bl1 = *(const bf16x8*)(wbl + wo + 512);
#pragma unroll
        for (int ti = 0; ti < 4; ti++) {
            int tile = wave + ti * 4;
            if (tile > 12) break;  // wave-uniform
            int addr = quad * 3696 + (pyr[ti] * 4 + ky) * 84 + oxr[ti] * 4;
            float4 a0 = *(const float4*)&xs[addr];
            float4 a1 = *(const float4*)&xs[addr + 4];
            float v[8] = {a0.x, a0.y, a0.z, a0.w, a1.x, a1.y, a1.z, a1.w};
            bf16x8 ah, al;
#pragma unroll
            for (int j = 0; j < 8; j++) {
                short hh, ll;
                split_trunc(v[j], hh, ll);
                ah[j] = hh;
                al[j] = ll;
            }
            acc[ti][0] = __builtin_amdgcn_mfma_f32_16x16x32_bf16(ah, bh0, acc[ti][0], 0, 0, 0);
            acc[ti][0] = __builtin_amdgcn_mfma_f32_16x16x32_bf16(al, bh0, acc[ti][0], 0, 0, 0);
            acc[ti][0] = __builtin_amdgcn_mfma_f32_16x16x32_bf16(ah, bl0, acc[ti][0], 0, 0, 0);
            acc[ti][1] = __builtin_amdgcn_mfma_f32_16x16x32_bf16(ah, bh1, acc[ti][1], 0, 0, 0);
            acc[ti][1] = __builtin_amdgcn_mfma_f32_16x16x32_bf16(al, bh1, acc[ti][1], 0, 0, 0);
            acc[ti][1] = __builtin_amdgcn_mfma_f32_16x16x32_bf16(ah, bl1, acc[ti][1], 0, 0, 0);
        }
    }
    float bias0 = b1[l16], bias1 = b1[16 + l16];
#pragma unroll
    for (int ti = 0; ti < 4; ti++) {
        int tile = wave + ti * 4;
        if (tile > 12) break;
#pragma unroll
        for (int r = 0; r < 4; r++) {
            int p = tile * 16 + quad * 4 + r;
            if (p < 200) {
                long o = ((long)n * 400 + h * 200 + p) * 32;
                float v0 = fmaxf(acc[ti][0][r] + bias0, 0.f);
                float v1 = fmaxf(acc[ti][1][r] + bias1, 0.f);
                short h0, l0, h1, l1;
                split_trunc(v0, h0, l0);
                split_trunc(v1, h1, l1);
                yhi[o + l16] = (unsigned short)h0;
                ylo[o + l16] = (unsigned short)l0;
                yhi[o + 16 + l16] = (unsigned short)h1;
                ylo[o + 16 + l16] = (unsigned short)l1;
            }
        }
    }
}

// ============ conv2/3: LDS-free implicit-GEMM, 1 wave per block ============
template <int C, int IH, int IW, int OH, int OW, int S, int KH, int KW>
__global__ __launch_bounds__(64, 3) void convm_k(
    const unsigned short* __restrict__ xhi, const unsigned short* __restrict__ xlo,
    const unsigned short* __restrict__ whi, const unsigned short* __restrict__ wlo,
    const float* __restrict__ bias,
    unsigned short* __restrict__ yhi, unsigned short* __restrict__ ylo) {
    constexpr int CH = C / 32;
    constexpr int NCHUNK = KH * KW * CH;
    int lane = threadIdx.x, l16 = lane & 15, quad = lane >> 4;
    int pxbase = blockIdx.x * 64;
    long xoff[4];
#pragma unroll
    for (int i = 0; i < 4; i++) {
        int px = pxbase + i * 16 + l16;
        int n = px / (OH * OW);
        int rem = px - n * (OH * OW);
        int oy = rem / OW;
        int ox = rem - oy * OW;
        xoff[i] = (((long)n * IH + oy * S) * IW + ox * S) * C + quad * 8;
    }
    f32x4 acc[4][4];
#pragma unroll
    for (int i = 0; i < 4; i++)
#pragma unroll
        for (int j = 0; j < 4; j++)
#pragma unroll
            for (int r = 0; r < 4; r++) acc[i][j][r] = 0.f;
#pragma unroll 2
    for (int ck = 0; ck < NCHUNK; ck++) {
        int kyx = ck / CH;
        int ch = ck - kyx * CH;
        int ky = kyx / KW, kx = kyx - ky * KW;
        long koff = ((long)(ky * IW + kx)) * C + ch * 32;
        bf16x8 ah[4], al[4], bh[4], bl[4];
#pragma unroll
        for (int i = 0; i < 4; i++) {
            ah[i] = *(const bf16x8*)(xhi + xoff[i] + koff);
            al[i] = *(const bf16x8*)(xlo + xoff[i] + koff);
        }
#pragma unroll
        for (int j = 0; j < 4; j++) {
            long b = ((long)ck * 64 + j * 16 + l16) * 32 + quad * 8;
            bh[j] = *(const bf16x8*)(whi + b);
            bl[j] = *(const bf16x8*)(wlo + b);
        }
#pragma unroll
        for (int i = 0; i < 4; i++)
#pragma unroll
            for (int j = 0; j < 4; j++) {
                acc[i][j] = __builtin_amdgcn_mfma_f32_16x16x32_bf16(ah[i], bh[j], acc[i][j], 0, 0, 0);
                acc[i][j] = __builtin_amdgcn_mfma_f32_16x16x32_bf16(ah[i], bl[j], acc[i][j], 0, 0, 0);
                acc[i][j] = __builtin_amdgcn_mfma_f32_16x16x32_bf16(al[i], bh[j], acc[i][j], 0, 0, 0);
            }
    }
#pragma unroll
    for (int i = 0; i < 4; i++)
#pragma unroll
        for (int j = 0; j < 4; j++) {
            int col = j * 16 + l16;
            float bv = bias[col];
#pragma unroll
            for (int r = 0; r < 4; r++) {
                int prow = pxbase + i * 16 + quad * 4 + r;
                float v = fmaxf(acc[i][j][r] + bv, 0.f);
                unsigned short hh = f2b(v);
                yhi[(long)prow * 64 + col] = hh;
                ylo[(long)prow * 64 + col] = f2b(v - b2f(hh));
            }
        }
}

// ============ fc: LDS-free split-bf16 MFMA, K-split x7; also zeroes cnt ============
__global__ __launch_bounds__(64, 3) void fc_k(
    const unsigned short* __restrict__ Ahi, const unsigned short* __restrict__ Alo,
    const unsigned short* __restrict__ Bhi, const unsigned short* __restrict__ Blo,
    float* __restrict__ Cp, int* __restrict__ cnt) {
    if (blockIdx.x == 0 && blockIdx.y == 0 && blockIdx.z == 0 && threadIdx.x < 8)
        cnt[threadIdx.x] = 0;
    int lane = threadIdx.x, l16 = lane & 15, quad = lane >> 4;
    int m0 = blockIdx.x * 64, n0 = blockIdx.y * 64;
    int z = blockIdx.z;
    int kBase = z * 448;
    f32x4 acc[4][4];
#pragma unroll
    for (int i = 0; i < 4; i++)
#pragma unroll
        for (int j = 0; j < 4; j++)
#pragma unroll
            for (int r = 0; r < 4; r++) acc[i][j][r] = 0.f;
#pragma unroll 2
    for (int k0 = kBase; k0 < kBase + 448; k0 += 32) {
        bf16x8 ah[4], al[4], bh[4], bl[4];
#pragma unroll
        for (int i = 0; i < 4; i++) {
            long a = (long)(m0 + i * 16 + l16) * 3136 + k0 + quad * 8;
            ah[i] = *(const bf16x8*)(Ahi + a);
            al[i] = *(const bf16x8*)(Alo + a);
        }
#pragma unroll
        for (int j = 0; j < 4; j++) {
            long b = (long)(n0 + j * 16 + l16) * 3136 + k0 + quad * 8;
            bh[j] = *(const bf16x8*)(Bhi + b);
            bl[j] = *(const bf16x8*)(Blo + b);
        }
#pragma unroll
        for (int i = 0; i < 4; i++)
#pragma unroll
            for (int j = 0; j < 4; j++) {
                acc[i][j] = __builtin_amdgcn_mfma_f32_16x16x32_bf16(ah[i], bh[j], acc[i][j], 0, 0, 0);
                acc[i][j] = __builtin_amdgcn_mfma_f32_16x16x32_bf16(ah[i], bl[j], acc[i][j], 0, 0, 0);
                acc[i][j] = __builtin_amdgcn_mfma_f32_16x16x32_bf16(al[i], bh[j], acc[i][j], 0, 0, 0);
            }
    }
    float* Cz = Cp + (long)z * 1048576;
#pragma unroll
    for (int i = 0; i < 4; i++)
#pragma unroll
        for (int j = 0; j < 4; j++) {
            int col = n0 + j * 16 + l16;
#pragma unroll
            for (int r = 0; r < 4; r++) {
                int row = m0 + i * 16 + quad * 4 + r;
                Cz[row * 512 + col] = acc[i][j][r];
            }
        }
}

// ============ fin_gate: sum partials + bias + relu + gate + top2 + bucket ============
__global__ __launch_bounds__(256) void fin_gate(
    const float* __restrict__ Cp, const float* __restrict__ bias,
    const float* __restrict__ gw, const float* __restrict__ gb,
    unsigned short* __restrict__ fb, int* __restrict__ topi, float* __restrict__ topp,
    int* __restrict__ cnt, int* __restrict__ list, int* __restrict__ pos) {
    int wave = threadIdx.x >> 6, lane = threadIdx.x & 63;
    int row = blockIdx.x * 4 + wave;
    float fv[8];
#pragma unroll
    for (int j = 0; j < 8; j++) {
        int col = lane + 64 * j;
        long idx = (long)row * 512 + col;
        float v = bias[col];
#pragma unroll
        for (int z = 0; z < 7; z++) v += Cp[idx + (long)z * 1048576];
        v = fmaxf(v, 0.f);
        fv[j] = v;
        fb[idx] = f2b(v);
    }
    float lg[6];
#pragma unroll
    for (int e = 0; e < 6; e++) {
        float a = 0.f;
#pragma unroll
        for (int j = 0; j < 8; j++) a += fv[j] * gw[(lane + 64 * j) * 6 + e];
#pragma unroll
        for (int off = 32; off > 0; off >>= 1) a += __shfl_xor(a, off, 64);
        lg[e] = a + gb[e];
    }
    if (lane == 0) {
        int i1 = 0;
        float v1 = lg[0];
#pragma unroll
        for (int e = 1; e < 6; e++)
            if (lg[e] > v1) { v1 = lg[e]; i1 = e; }
        int i2 = (i1 == 0) ? 1 : 0;
        float v2 = lg[i2];
#pragma unroll
        for (int e = 0; e < 6; e++)
            if (e != i1 && lg[e] > v2) { v2 = lg[e]; i2 = e; }
        float pa = 1.f / (1.f + expf(v2 - v1));
        topi[row * 2] = i1;
        topi[row * 2 + 1] = i2;
        topp[row * 2] = pa;
        topp[row * 2 + 1] = 1.f - pa;
        int s0 = atomicAdd(&cnt[i1], 1);
        list[i1 * 2048 + s0] = row;
        pos[row * 2] = s0;
        int s1 = atomicAdd(&cnt[i2], 1);
        list[i2 * 2048 + s1] = row;
        pos[row * 2 + 1] = s1;
    }
}

// ============ expert GEMM: LDS-free, top-2-only (M = cnt[e]), optional row gather ============
__global__ __launch_bounds__(64, 4) void moe_gemm(
    const unsigned short* __restrict__ A, long aStride, int gather,
    const unsigned short* __restrict__ Bt, const float* __restrict__ bias,
    const int* __restrict__ cnt, const int* __restrict__ list,
    unsigned short* __restrict__ C) {
    int e = blockIdx.z;
    int M = cnt[e];
    int m0 = blockIdx.x * 64;
    if (m0 >= M) return;
    const unsigned short* Ae = A + (long)e * aStride;
    const unsigned short* Be = Bt + (long)e * 262144;
    const float* be = bias + e * 512;
    unsigned short* Ce = C + (long)e * 1048576;
    int lane = threadIdx.x, l16 = lane & 15, quad = lane >> 4;
    int n0 = blockIdx.y * 64;
    long abase[4];
#pragma unroll
    for (int i = 0; i < 4; i++) {
        int idx = m0 + i * 16 + l16;
        idx = idx < M ? idx : M - 1;
        int row = gather ? list[e * 2048 + idx] : idx;
        abase[i] = (long)row * 512;
    }
    f32x4 acc[4][4];
#pragma unroll
    for (int i = 0; i < 4; i++)
#pragma unroll
        for (int j = 0; j < 4; j++)
#pragma unroll
            for (int r = 0; r < 4; r++) acc[i][j][r] = 0.f;
#pragma unroll 4
    for (int k0 = 0; k0 < 512; k0 += 32) {
        bf16x8 a[4], b[4];
#pragma unroll
        for (int i = 0; i < 4; i++)
            a[i] = *(const bf16x8*)(Ae + abase[i] + k0 + quad * 8);
#pragma unroll
        for (int j = 0; j < 4; j++)
            b[j] = *(const bf16x8*)(Be + (long)(n0 + j * 16 + l16) * 512 + k0 + quad * 8);
#pragma unroll
        for (int i = 0; i < 4; i++)
#pragma unroll
            for (int j = 0; j < 4; j++)
                acc[i][j] = __builtin_amdgcn_mfma_f32_16x16x32_bf16(a[i], b[j], acc[i][j], 0, 0, 0);
    }
#pragma unroll
    for (int i = 0; i < 4; i++)
#pragma unroll
        for (int j = 0; j < 4; j++) {
            int col = n0 + j * 16 + l16;
            float bcol = be[col];
#pragma unroll
            for (int r = 0; r < 4; r++) {
                int idx = m0 + i * 16 + quad * 4 + r;
                if (idx < M) {
                    float v = fmaxf(acc[i][j][r] + bcol, 0.f);
                    Ce[(long)idx * 512 + col] = f2b(v);
                }
            }
        }
}

// ============ combine: wave per row, slot-indexed compact h2 ============
__global__ __launch_bounds__(256) void combine_k(
    const unsigned short* __restrict__ h2, const float* __restrict__ w3t,
    const float* __restrict__ b3, const int* __restrict__ topi,
    const int* __restrict__ pos, const float* __restrict__ topp,
    float* __restrict__ out) {
    int b = blockIdx.x * 4 + (threadIdx.x >> 6);
    int lane = threadIdx.x & 63;
    int e0 = topi[b * 2], e1 = topi[b * 2 + 1];
    float p0 = topp[b * 2], p1 = topp[b * 2 + 1];
    float r[12];
#pragma unroll
    for (int a = 0; a < 12; a++) r[a] = 0.f;
#pragma unroll
    for (int j = 0; j < 2; j++) {
        int e = j ? e1 : e0;
        float p = j ? p1 : p0;
        int s = pos[b * 2 + j];
        const unsigned short* hp = h2 + ((long)e * 2048 + s) * 512 + lane * 8;
        bf16x8 hv = *(const bf16x8*)hp;
        float hf[8];
#pragma unroll
        for (int q = 0; q < 8; q++) hf[q] = b2f((unsigned short)hv[q]);
        const float* wb = w3t + e * 6144 + lane * 8;
#pragma unroll
        for (int a = 0; a < 12; a++) {
            float4 w0 = *(const float4*)(wb + a * 512);
            float4 w1 = *(const float4*)(wb + a * 512 + 4);
            float acc = hf[0] * w0.x + hf[1] * w0.y + hf[2] * w0.z + hf[3] * w0.w +
                        hf[4] * w1.x + hf[5] * w1.y + hf[6] * w1.z + hf[7] * w1.w;
            r[a] += p * acc;
        }
    }
#pragma unroll
    for (int a = 0; a < 12; a++)
#pragma unroll
        for (int off = 32; off > 0; off >>= 1) r[a] += __shfl_xor(r[a], off, 64);
    float v = 0.f;
#pragma unroll
    for (int a = 0; a < 12; a++)
        if (lane == a) v = r[a];
    if (lane < 12)
        out[b * 12 + lane] = v + p0 * b3[e0 * 12 + lane] + p1 * b3[e1 * 12 + lane];
}

extern "C" void kernel_launch(void* const* d_in, const int* in_sizes, int n_in,
                              void* d_out, int out_size, void* d_ws, size_t ws_size,
                              hipStream_t stream) {
    const float* x   = (const float*)d_in[0];
    const float* c1w = (const float*)d_in[1];
    const float* c1b = (const float*)d_in[2];
    const float* c2w = (const float*)d_in[3];
    const float* c2b = (const float*)d_in[4];
    const float* c3w = (const float*)d_in[5];
    const float* c3b = (const float*)d_in[6];
    const float* fcw = (const float*)d_in[7];
    const float* fcb = (const float*)d_in[8];
    const float* gw  = (const float*)d_in[9];
    const float* gb  = (const float*)d_in[10];
    const float* ew1 = (const float*)d_in[11];
    const float* eb1 = (const float*)d_in[12];
    const float* ew2 = (const float*)d_in[13];
    const float* eb2 = (const float*)d_in[14];
    const float* ew3 = (const float*)d_in[15];
    const float* eb3 = (const float*)d_in[16];

    char* ws = (char*)d_ws;
    unsigned short* y1hi = (unsigned short*)(ws + 0L);          // 52428800 B
    unsigned short* y1lo = (unsigned short*)(ws + 52428800L);   // 52428800 B
    unsigned short* f3hi = (unsigned short*)(ws + 0L);          // alias (y1 dead after conv2)
    unsigned short* f3lo = (unsigned short*)(ws + 12845056L);   // alias
    unsigned short* y2hi = (unsigned short*)(ws + 104857600L);  // 21233664 B
    unsigned short* y2lo = (unsigned short*)(ws + 126091264L);  // 21233664 B
    unsigned short* h1   = (unsigned short*)(ws + 104857600L);  // alias (y2 dead after conv3)
    unsigned short* h2   = (unsigned short*)(ws + 117440512L);  // alias
    unsigned short* fb   = (unsigned short*)(ws + 151519232L);  // 2097152 B
    int*   topi          = (int*)(ws + 153616384L);             // 16384 B
    float* topp          = (float*)(ws + 153632768L);           // 16384 B
    unsigned short* w2h  = (unsigned short*)(ws + 153681920L);  // 65536 B
    unsigned short* w2l  = (unsigned short*)(ws + 153747456L);  // 65536 B
    unsigned short* w3h  = (unsigned short*)(ws + 153812992L);  // 73728 B
    unsigned short* w3l  = (unsigned short*)(ws + 153886720L);  // 73728 B
    unsigned short* fcwh = (unsigned short*)(ws + 153960448L);  // 3211264 B
    unsigned short* fcwl = (unsigned short*)(ws + 157171712L);  // 3211264 B
    unsigned short* ew1t = (unsigned short*)(ws + 160382976L);  // 3145728 B
    unsigned short* ew2t = (unsigned short*)(ws + 163528704L);  // 3145728 B
    float* w3t           = (float*)(ws + 166674432L);           // 147456 B
    float* Cp            = (float*)(ws + 166821888L);           // 29360128 B
    unsigned short* wb1h = (unsigned short*)(ws + 196182016L);  // 16384 B
    unsigned short* wb1l = (unsigned short*)(ws + 196198400L);  // 16384 B
    int* list            = (int*)(ws + 196214784L);             // 49152 B
    int* pos             = (int*)(ws + 196263936L);             // 16384 B
    int* cnt             = (int*)(ws + 196280320L);             // 64 B (end 196280384)
    float* out = (float*)d_out;

    hipLaunchKernelGGL(prep_all, dim3(3912), dim3(256), 0, stream,
                       c1w, c2w, c3w, ew3, fcw, ew1, ew2,
                       wb1h, wb1l, w2h, w2l, w3h, w3l, w3t, fcwh, fcwl, ew1t, ew2t);
    hipLaunchKernelGGL(conv1_k, dim3(4096), dim3(256), 0, stream, x, wb1h, wb1l, c1b, y1hi, y1lo);
    hipLaunchKernelGGL((convm_k<32, 20, 20, 9, 9, 2, 4, 4>), dim3(2592), dim3(64), 0, stream,
                       y1hi, y1lo, w2h, w2l, c2b, y2hi, y2lo);
    hipLaunchKernelGGL((convm_k<64, 9, 9, 7, 7, 1, 3, 3>), dim3(1568), dim3(64), 0, stream,
                       y2hi, y2lo, w3h, w3l, c3b, f3hi, f3lo);
    hipLaunchKernelGGL(fc_k, dim3(32, 8, 7), dim3(64), 0, stream, f3hi, f3lo, fcwh, fcwl, Cp, cnt);
    hipLaunchKernelGGL(fin_gate, dim3(512), dim3(256), 0, stream, Cp, fcb, gw, gb,
                       fb, topi, topp, cnt, list, pos);
    hipLaunchKernelGGL(moe_gemm, dim3(32, 8, 6), dim3(64), 0, stream,
                       fb, 0L, 1, ew1t, eb1, cnt, list, h1);
    hipLaunchKernelGGL(moe_gemm, dim3(32, 8, 6), dim3(64), 0, stream,
                       h1, 1048576L, 0, ew2t, eb2, cnt, list, h2);
    hipLaunchKernelGGL(combine_k, dim3(512), dim3(256), 0, stream,
                       h2, w3t, eb3, topi, pos, topp, out);
}